// Round 11
// baseline (444.965 us; speedup 1.0000x reference)
//
#include <hip/hip_runtime.h>

#define T_ 12
#define N_ 1370
#define MSEQ 32      // sequences per block
#define LDA 72       // h LDS row stride in shorts (144B -> 2-way banks max)
#define NBLK 2740    // 87680 / 32

typedef __attribute__((ext_vector_type(8))) short short8;
typedef __attribute__((ext_vector_type(4))) float floatx4;

#define NLOG2E -1.4426950408889634f
#define TLOG2E 2.8853900817779268f
#define N2LOG2E -5.7707801635558536f   // -2*TLOG2E

__device__ __forceinline__ short f2bf(float x) {
  unsigned u = __builtin_bit_cast(unsigned, x);
  u = (u + 0x7fffu + ((u >> 16) & 1u)) >> 16;
  return (short)u;
}
// HW packed f32->bf16: low16 = bf16(a), high16 = bf16(b)
__device__ __forceinline__ unsigned pk_bf16(float a, float b) {
  unsigned r;
  asm("v_cvt_pk_bf16_f32 %0, %1, %2" : "=v"(r) : "v"(a), "v"(b));
  return r;
}
__device__ __forceinline__ short8 load_w8s(const float* __restrict__ p, float s) {
  short8 r;
#pragma unroll
  for (int j = 0; j < 8; ++j) r[j] = f2bf(p[j] * s);
  return r;
}

// R10 kernel (passing, 102us, VGPR=64, zero spill) with ONE change:
// __launch_bounds__(256,4) -> (256,8). Empirically the waves-per-eu arg has
// acted as the RESIDENCY CAP all session (Occ% ~= 0.75 * 4*wpe/32 for
// wpe=2,3,4,6 across R2/R7/R8/R9/R10) -- we were self-capped at ~3
// blocks/CU, which the fill model says is exactly the 55-63% VALUBusy we
// measure. At 8 waves/EU the VGPR budget is 512/8 = 64 = exactly what this
// body compiles to, so no allocator squeeze; LDS 15.9KB x 8 = 127KB < 160;
// wave slots 32 = 8 blocks x 4 waves. Expect occupancy ~2x, fill -> 80%+.
// Numerics identical (absmax 1.953e-3): weights pre-scaled (i,f,o by
// -log2e, g by 2*log2e), grouped reciprocals, cell state pre-scaled by
// 2*log2e. Compact x staging + broadcast ones_row.
__global__ void __launch_bounds__(256, 8) lstm_kernel(
    const float* __restrict__ x, const float* __restrict__ W_ih,
    const float* __restrict__ W_hh, const float* __restrict__ b_ih,
    const float* __restrict__ b_hh, const float* __restrict__ W_fc,
    const float* __restrict__ b_fc, float* __restrict__ out) {
  __shared__ short hbuf[2][MSEQ][LDA];                 // 9216 B
  __shared__ __align__(16) short xbuf[T_][MSEQ][8];    // 6144 B
  __shared__ __align__(16) short ones_row[8];          //   16 B

  const int tid = threadIdx.x;
  const int wave = tid >> 6;
  const int lane = tid & 63;
  const int m16 = lane & 15;
  const int q = lane >> 4;
  const int blk = blockIdx.x;

  // ---- A-operand weight fragments: lane row = unit wave*16+m16 ----
  const int urow = wave * 16 + m16;
  short8 wA[4][3];
#pragma unroll
  for (int g = 0; g < 4; ++g) {
    const float sg = (g == 2) ? TLOG2E : NLOG2E;
    const int grow = g * 64 + urow;
    const float* wr = W_hh + grow * 64;
    wA[g][0] = load_w8s(wr + q * 8, sg);
    wA[g][1] = load_w8s(wr + 32 + q * 8, sg);
    short8 z = {0, 0, 0, 0, 0, 0, 0, 0};
    if (q == 0) {
      wA[g][2] = load_w8s(W_ih + grow * 8, sg);  // k=64..71: x columns
    } else if (q == 1) {
      z[0] = f2bf(sg * (b_ih[grow] + b_hh[grow]));  // k=72: bias column
      wA[g][2] = z;
    } else {
      wA[g][2] = z;  // k=80..95 dead
    }
  }

  // ---- zero hbuf (h0 = 0, pads = 0); ones row for bias column ----
  {
    int* hp = (int*)hbuf;
#pragma unroll
    for (int i = tid; i < (2 * MSEQ * LDA) / 2; i += 256) hp[i] = 0;
    if (tid < 8) ones_row[tid] = (tid == 0) ? (short)0x3F80 : (short)0;
  }
  __syncthreads();

  // ---- stage all 12 timesteps of x as bf16 (compact 16B rows) ----
  {
    const int xseq = tid >> 3, xc = tid & 7;
    const int s0 = blk * MSEQ + xseq;
    const int bidx = s0 / N_;
    const int nidx = s0 - bidx * N_;
    const float* xp = x + ((size_t)(bidx * T_) * N_ + nidx) * 8 + xc;
#pragma unroll
    for (int t = 0; t < T_; ++t)
      xbuf[t][xseq][xc] = f2bf(xp[(size_t)t * (N_ * 8)]);
  }
  __syncthreads();

  const floatx4 zacc = {0.0f, 0.0f, 0.0f, 0.0f};

  float cst[2][4];
#pragma unroll
  for (int nt = 0; nt < 2; ++nt)
#pragma unroll
    for (int r = 0; r < 4; ++r) cst[nt][r] = 0.0f;

  for (int t = 0; t < T_; ++t) {
    const int rb = t & 1, wb = rb ^ 1;

    // ---- phase 1: all LDS reads ----
    short8 b0[2], b1[2], bx[2];
#pragma unroll
    for (int nt = 0; nt < 2; ++nt) {
      const int srow = nt * 16 + m16;
      b0[nt] = *(const short8*)&hbuf[rb][srow][q * 8];
      b1[nt] = *(const short8*)&hbuf[rb][srow][32 + q * 8];
      const short* bxp = q ? &ones_row[0] : &xbuf[t][srow][0];
      bx[nt] = *(const short8*)bxp;
    }

    // ---- phase 2: all 24 MFMAs into materialized accumulators ----
    floatx4 acc[2][4];
#pragma unroll
    for (int nt = 0; nt < 2; ++nt)
#pragma unroll
      for (int g = 0; g < 4; ++g) {
        floatx4 c = __builtin_amdgcn_mfma_f32_16x16x32_bf16(wA[g][0], b0[nt], zacc, 0, 0, 0);
        c = __builtin_amdgcn_mfma_f32_16x16x32_bf16(wA[g][1], b1[nt], c, 0, 0, 0);
        c = __builtin_amdgcn_mfma_f32_16x16x32_bf16(wA[g][2], bx[nt], c, 0, 0, 0);
        acc[nt][g] = c;
      }

    // ---- phase 3a: all 32 gate exp2 (independent, stream the trans pipe)
    float di[2][4], df[2][4], dgv[2][4], dqv[2][4];
#pragma unroll
    for (int nt = 0; nt < 2; ++nt)
#pragma unroll
      for (int r = 0; r < 4; ++r) {
        di[nt][r] = 1.0f + __builtin_amdgcn_exp2f(acc[nt][0][r]);
        df[nt][r] = 1.0f + __builtin_amdgcn_exp2f(acc[nt][1][r]);
        dgv[nt][r] = 1.0f + __builtin_amdgcn_exp2f(acc[nt][2][r]);
        dqv[nt][r] = 1.0f + __builtin_amdgcn_exp2f(acc[nt][3][r]);
      }

    // ---- phase 3b: grouped rp across the nt pair (4 rcp instead of 8)
    float pa[2][4], pb[2][4], rp[2][4];
#pragma unroll
    for (int r = 0; r < 4; ++r) {
      pa[0][r] = di[0][r] * df[0][r];
      pb[0][r] = dgv[0][r] * dqv[0][r];
      pa[1][r] = di[1][r] * df[1][r];
      pb[1][r] = dgv[1][r] * dqv[1][r];
      const float PA = pa[0][r] * pb[0][r];
      const float PB = pa[1][r] * pb[1][r];
      const float R = __builtin_amdgcn_rcpf(PA * PB);
      rp[0][r] = R * PB;
      rp[1][r] = R * PA;
    }

    // ---- phase 3c: gate algebra + cell update + tanh-denominator exp2
    float ov[2][4], dt[2][4];
#pragma unroll
    for (int nt = 0; nt < 2; ++nt)
#pragma unroll
      for (int r = 0; r < 4; ++r) {
        const float fv = rp[nt][r] * di[nt][r] * pb[nt][r];      // f = 1/df
        ov[nt][r] = rp[nt][r] * pa[nt][r] * dgv[nt][r];          // o = 1/dq
        const float tg = fmaf(TLOG2E, dgv[nt][r], N2LOG2E);      // (dg-2)*2log2e
        const float ig = tg * rp[nt][r] * (df[nt][r] * dqv[nt][r]);
        const float cs = fmaf(fv, cst[nt][r], ig);               // c*2log2e
        cst[nt][r] = cs;
        dt[nt][r] = 1.0f + __builtin_amdgcn_exp2f(cs);
      }

    // ---- phase 3d: grouped tanh reciprocal per nt (1 rcp for 4 cells)
    unsigned long long pkv[2];
#pragma unroll
    for (int nt = 0; nt < 2; ++nt) {
      const float m01 = dt[nt][0] * dt[nt][1];
      const float m23 = dt[nt][2] * dt[nt][3];
      const float R = __builtin_amdgcn_rcpf(m01 * m23);
      const float r01 = R * m23, r23 = R * m01;
      float rdt[4];
      rdt[0] = r01 * dt[nt][1];
      rdt[1] = r01 * dt[nt][0];
      rdt[2] = r23 * dt[nt][3];
      rdt[3] = r23 * dt[nt][2];
      float hv[4];
#pragma unroll
      for (int r = 0; r < 4; ++r) {
        const float tw = ov[nt][r] + ov[nt][r];                  // 2*o
        hv[r] = fmaf(-tw, rdt[r], ov[nt][r]);                    // o*(1-2/dt)
      }
      pkv[nt] = (unsigned long long)pk_bf16(hv[0], hv[1]) |
                ((unsigned long long)pk_bf16(hv[2], hv[3]) << 32);
    }

    // ---- phase 4: h writes + barrier ----
#pragma unroll
    for (int nt = 0; nt < 2; ++nt) {
      const int srow = nt * 16 + m16;
      *(unsigned long long*)&hbuf[wb][srow][wave * 16 + q * 4] = pkv[nt];
    }
    __syncthreads();
  }

  // ---- final FC: y = h_T @ W_fc^T + b_fc; h_T is in hbuf[0] ----
  if (wave < 2) {
    short8 f0, f1;
    short8 z = {0, 0, 0, 0, 0, 0, 0, 0};
    if (m16 < 8) {
      const float* wr = W_fc + m16 * 64;
      f0 = load_w8s(wr + q * 8, 1.0f);
      f1 = load_w8s(wr + 32 + q * 8, 1.0f);
    } else {
      f0 = z;
      f1 = z;
    }
    const int srow = wave * 16 + m16;
    short8 h0 = *(const short8*)&hbuf[0][srow][q * 8];
    short8 h1 = *(const short8*)&hbuf[0][srow][32 + q * 8];
    floatx4 acc = __builtin_amdgcn_mfma_f32_16x16x32_bf16(f0, h0, zacc, 0, 0, 0);
    acc = __builtin_amdgcn_mfma_f32_16x16x32_bf16(f1, h1, acc, 0, 0, 0);
    if (q < 2) {
      const int orow = blk * MSEQ + srow;
#pragma unroll
      for (int r = 0; r < 4; ++r)
        out[orow * 8 + q * 4 + r] = acc[r] + b_fc[q * 4 + r];
    }
  }
}

extern "C" void kernel_launch(void* const* d_in, const int* in_sizes, int n_in,
                              void* d_out, int out_size, void* d_ws,
                              size_t ws_size, hipStream_t stream) {
  const float* x    = (const float*)d_in[0];
  const float* W_ih = (const float*)d_in[1];
  const float* W_hh = (const float*)d_in[2];
  const float* b_ih = (const float*)d_in[3];
  const float* b_hh = (const float*)d_in[4];
  const float* W_fc = (const float*)d_in[5];
  const float* b_fc = (const float*)d_in[6];
  float* out = (float*)d_out;
  hipLaunchKernelGGL(lstm_kernel, dim3(NBLK), dim3(256), 0, stream,
                     x, W_ih, W_hh, b_ih, b_hh, W_fc, b_fc, out);
}

// Round 12
// 162.722 us; speedup vs baseline: 2.7345x; 2.7345x over previous
//
#include <hip/hip_runtime.h>

#define T_ 12
#define N_ 1370
#define MSEQ 32      // sequences per block
#define LDA 72       // h LDS row stride in shorts (144B -> 2-way banks max)
#define NBLK 2740    // 87680 / 32

typedef __attribute__((ext_vector_type(8))) short short8;
typedef __attribute__((ext_vector_type(4))) float floatx4;

#define NLOG2E -1.4426950408889634f
#define TLOG2E 2.8853900817779268f
#define N2LOG2E -5.7707801635558536f   // -2*TLOG2E

__device__ __forceinline__ short f2bf(float x) {
  unsigned u = __builtin_bit_cast(unsigned, x);
  u = (u + 0x7fffu + ((u >> 16) & 1u)) >> 16;
  return (short)u;
}
// HW packed f32->bf16: low16 = bf16(a), high16 = bf16(b)
__device__ __forceinline__ unsigned pk_bf16(float a, float b) {
  unsigned r;
  asm("v_cvt_pk_bf16_f32 %0, %1, %2" : "=v"(r) : "v"(a), "v"(b));
  return r;
}
__device__ __forceinline__ short8 load_w8s(const float* __restrict__ p, float s) {
  short8 r;
#pragma unroll
  for (int j = 0; j < 8; ++j) r[j] = f2bf(p[j] * s);
  return r;
}

// R10 body (passing, 102us, VGPR=64, zero spill) with __launch_bounds__
// REMOVED. Session-wide evidence: compiled VGPR = min(body-need=64,
// 256/wpe) and measured residency ~= 0.75*wpe blocks/CU -- the wpe arg
// both capped residency (R7/R8/R10: 3 blocks @ 37%) and, when raised,
// strangled the allocator (R9: wpe=6 -> 40 VGPR spill; R11: wpe=8 -> 32
// VGPR spill, 382us despite 74% occupancy). Removing the attribute lets
// the allocator take exactly the ~64 the body needs AND lets HW derive
// residency from real resources (LDS 15.9KB -> 10 blocks, wave slots ->
// 8 blocks, VGPR pool -> 4-8 waves/SIMD). Decisive occupancy read.
// Numerics identical (absmax 1.953e-3): weights pre-scaled (i,f,o by
// -log2e, g by 2*log2e), grouped reciprocals, cell state pre-scaled by
// 2*log2e. Compact x staging + broadcast ones_row.
__global__ void lstm_kernel(
    const float* __restrict__ x, const float* __restrict__ W_ih,
    const float* __restrict__ W_hh, const float* __restrict__ b_ih,
    const float* __restrict__ b_hh, const float* __restrict__ W_fc,
    const float* __restrict__ b_fc, float* __restrict__ out) {
  __shared__ short hbuf[2][MSEQ][LDA];                 // 9216 B
  __shared__ __align__(16) short xbuf[T_][MSEQ][8];    // 6144 B
  __shared__ __align__(16) short ones_row[8];          //   16 B

  const int tid = threadIdx.x;
  const int wave = tid >> 6;
  const int lane = tid & 63;
  const int m16 = lane & 15;
  const int q = lane >> 4;
  const int blk = blockIdx.x;

  // ---- A-operand weight fragments: lane row = unit wave*16+m16 ----
  const int urow = wave * 16 + m16;
  short8 wA[4][3];
#pragma unroll
  for (int g = 0; g < 4; ++g) {
    const float sg = (g == 2) ? TLOG2E : NLOG2E;
    const int grow = g * 64 + urow;
    const float* wr = W_hh + grow * 64;
    wA[g][0] = load_w8s(wr + q * 8, sg);
    wA[g][1] = load_w8s(wr + 32 + q * 8, sg);
    short8 z = {0, 0, 0, 0, 0, 0, 0, 0};
    if (q == 0) {
      wA[g][2] = load_w8s(W_ih + grow * 8, sg);  // k=64..71: x columns
    } else if (q == 1) {
      z[0] = f2bf(sg * (b_ih[grow] + b_hh[grow]));  // k=72: bias column
      wA[g][2] = z;
    } else {
      wA[g][2] = z;  // k=80..95 dead
    }
  }

  // ---- zero hbuf (h0 = 0, pads = 0); ones row for bias column ----
  {
    int* hp = (int*)hbuf;
#pragma unroll
    for (int i = tid; i < (2 * MSEQ * LDA) / 2; i += 256) hp[i] = 0;
    if (tid < 8) ones_row[tid] = (tid == 0) ? (short)0x3F80 : (short)0;
  }
  __syncthreads();

  // ---- stage all 12 timesteps of x as bf16 (compact 16B rows) ----
  {
    const int xseq = tid >> 3, xc = tid & 7;
    const int s0 = blk * MSEQ + xseq;
    const int bidx = s0 / N_;
    const int nidx = s0 - bidx * N_;
    const float* xp = x + ((size_t)(bidx * T_) * N_ + nidx) * 8 + xc;
#pragma unroll
    for (int t = 0; t < T_; ++t)
      xbuf[t][xseq][xc] = f2bf(xp[(size_t)t * (N_ * 8)]);
  }
  __syncthreads();

  const floatx4 zacc = {0.0f, 0.0f, 0.0f, 0.0f};

  float cst[2][4];
#pragma unroll
  for (int nt = 0; nt < 2; ++nt)
#pragma unroll
    for (int r = 0; r < 4; ++r) cst[nt][r] = 0.0f;

  for (int t = 0; t < T_; ++t) {
    const int rb = t & 1, wb = rb ^ 1;

    // ---- phase 1: all LDS reads ----
    short8 b0[2], b1[2], bx[2];
#pragma unroll
    for (int nt = 0; nt < 2; ++nt) {
      const int srow = nt * 16 + m16;
      b0[nt] = *(const short8*)&hbuf[rb][srow][q * 8];
      b1[nt] = *(const short8*)&hbuf[rb][srow][32 + q * 8];
      const short* bxp = q ? &ones_row[0] : &xbuf[t][srow][0];
      bx[nt] = *(const short8*)bxp;
    }

    // ---- phase 2: all 24 MFMAs into materialized accumulators ----
    floatx4 acc[2][4];
#pragma unroll
    for (int nt = 0; nt < 2; ++nt)
#pragma unroll
      for (int g = 0; g < 4; ++g) {
        floatx4 c = __builtin_amdgcn_mfma_f32_16x16x32_bf16(wA[g][0], b0[nt], zacc, 0, 0, 0);
        c = __builtin_amdgcn_mfma_f32_16x16x32_bf16(wA[g][1], b1[nt], c, 0, 0, 0);
        c = __builtin_amdgcn_mfma_f32_16x16x32_bf16(wA[g][2], bx[nt], c, 0, 0, 0);
        acc[nt][g] = c;
      }

    // ---- phase 3a: all 32 gate exp2 (independent, stream the trans pipe)
    float di[2][4], df[2][4], dgv[2][4], dqv[2][4];
#pragma unroll
    for (int nt = 0; nt < 2; ++nt)
#pragma unroll
      for (int r = 0; r < 4; ++r) {
        di[nt][r] = 1.0f + __builtin_amdgcn_exp2f(acc[nt][0][r]);
        df[nt][r] = 1.0f + __builtin_amdgcn_exp2f(acc[nt][1][r]);
        dgv[nt][r] = 1.0f + __builtin_amdgcn_exp2f(acc[nt][2][r]);
        dqv[nt][r] = 1.0f + __builtin_amdgcn_exp2f(acc[nt][3][r]);
      }

    // ---- phase 3b: grouped rp across the nt pair (4 rcp instead of 8)
    float pa[2][4], pb[2][4], rp[2][4];
#pragma unroll
    for (int r = 0; r < 4; ++r) {
      pa[0][r] = di[0][r] * df[0][r];
      pb[0][r] = dgv[0][r] * dqv[0][r];
      pa[1][r] = di[1][r] * df[1][r];
      pb[1][r] = dgv[1][r] * dqv[1][r];
      const float PA = pa[0][r] * pb[0][r];
      const float PB = pa[1][r] * pb[1][r];
      const float R = __builtin_amdgcn_rcpf(PA * PB);
      rp[0][r] = R * PB;
      rp[1][r] = R * PA;
    }

    // ---- phase 3c: gate algebra + cell update + tanh-denominator exp2
    float ov[2][4], dt[2][4];
#pragma unroll
    for (int nt = 0; nt < 2; ++nt)
#pragma unroll
      for (int r = 0; r < 4; ++r) {
        const float fv = rp[nt][r] * di[nt][r] * pb[nt][r];      // f = 1/df
        ov[nt][r] = rp[nt][r] * pa[nt][r] * dgv[nt][r];          // o = 1/dq
        const float tg = fmaf(TLOG2E, dgv[nt][r], N2LOG2E);      // (dg-2)*2log2e
        const float ig = tg * rp[nt][r] * (df[nt][r] * dqv[nt][r]);
        const float cs = fmaf(fv, cst[nt][r], ig);               // c*2log2e
        cst[nt][r] = cs;
        dt[nt][r] = 1.0f + __builtin_amdgcn_exp2f(cs);
      }

    // ---- phase 3d: grouped tanh reciprocal per nt (1 rcp for 4 cells)
    unsigned long long pkv[2];
#pragma unroll
    for (int nt = 0; nt < 2; ++nt) {
      const float m01 = dt[nt][0] * dt[nt][1];
      const float m23 = dt[nt][2] * dt[nt][3];
      const float R = __builtin_amdgcn_rcpf(m01 * m23);
      const float r01 = R * m23, r23 = R * m01;
      float rdt[4];
      rdt[0] = r01 * dt[nt][1];
      rdt[1] = r01 * dt[nt][0];
      rdt[2] = r23 * dt[nt][3];
      rdt[3] = r23 * dt[nt][2];
      float hv[4];
#pragma unroll
      for (int r = 0; r < 4; ++r) {
        const float tw = ov[nt][r] + ov[nt][r];                  // 2*o
        hv[r] = fmaf(-tw, rdt[r], ov[nt][r]);                    // o*(1-2/dt)
      }
      pkv[nt] = (unsigned long long)pk_bf16(hv[0], hv[1]) |
                ((unsigned long long)pk_bf16(hv[2], hv[3]) << 32);
    }

    // ---- phase 4: h writes + barrier ----
#pragma unroll
    for (int nt = 0; nt < 2; ++nt) {
      const int srow = nt * 16 + m16;
      *(unsigned long long*)&hbuf[wb][srow][wave * 16 + q * 4] = pkv[nt];
    }
    __syncthreads();
  }

  // ---- final FC: y = h_T @ W_fc^T + b_fc; h_T is in hbuf[0] ----
  if (wave < 2) {
    short8 f0, f1;
    short8 z = {0, 0, 0, 0, 0, 0, 0, 0};
    if (m16 < 8) {
      const float* wr = W_fc + m16 * 64;
      f0 = load_w8s(wr + q * 8, 1.0f);
      f1 = load_w8s(wr + 32 + q * 8, 1.0f);
    } else {
      f0 = z;
      f1 = z;
    }
    const int srow = wave * 16 + m16;
    short8 h0 = *(const short8*)&hbuf[0][srow][q * 8];
    short8 h1 = *(const short8*)&hbuf[0][srow][32 + q * 8];
    floatx4 acc = __builtin_amdgcn_mfma_f32_16x16x32_bf16(f0, h0, zacc, 0, 0, 0);
    acc = __builtin_amdgcn_mfma_f32_16x16x32_bf16(f1, h1, acc, 0, 0, 0);
    if (q < 2) {
      const int orow = blk * MSEQ + srow;
#pragma unroll
      for (int r = 0; r < 4; ++r)
        out[orow * 8 + q * 4 + r] = acc[r] + b_fc[q * 4 + r];
    }
  }
}

extern "C" void kernel_launch(void* const* d_in, const int* in_sizes, int n_in,
                              void* d_out, int out_size, void* d_ws,
                              size_t ws_size, hipStream_t stream) {
  const float* x    = (const float*)d_in[0];
  const float* W_ih = (const float*)d_in[1];
  const float* W_hh = (const float*)d_in[2];
  const float* b_ih = (const float*)d_in[3];
  const float* b_hh = (const float*)d_in[4];
  const float* W_fc = (const float*)d_in[5];
  const float* b_fc = (const float*)d_in[6];
  float* out = (float*)d_out;
  hipLaunchKernelGGL(lstm_kernel, dim3(NBLK), dim3(256), 0, stream,
                     x, W_ih, W_hh, b_ih, b_hh, W_fc, b_fc, out);
}

// Round 13
// 161.978 us; speedup vs baseline: 2.7471x; 1.0046x over previous
//
#include <hip/hip_runtime.h>

#define T_ 12
#define N_ 1370
#define MSEQ 32      // sequences per block
#define LDA 72       // h LDS row stride in shorts (144B -> 2-way banks max)
#define NBLK 2740    // 87680 / 32

typedef __attribute__((ext_vector_type(4))) short short4v;
typedef __attribute__((ext_vector_type(8))) short short8;
typedef __attribute__((ext_vector_type(4))) float floatx4;

#define NLOG2E -1.4426950408889634f
#define TLOG2E 2.8853900817779268f
#define N2LOG2E -5.7707801635558536f   // -2*TLOG2E

__device__ __forceinline__ short f2bf(float x) {
  unsigned u = __builtin_bit_cast(unsigned, x);
  u = (u + 0x7fffu + ((u >> 16) & 1u)) >> 16;
  return (short)u;
}
// HW packed f32->bf16: low16 = bf16(a), high16 = bf16(b)
__device__ __forceinline__ unsigned pk_bf16(float a, float b) {
  unsigned r;
  asm("v_cvt_pk_bf16_f32 %0, %1, %2" : "=v"(r) : "v"(a), "v"(b));
  return r;
}
__device__ __forceinline__ short8 load_w8s(const float* __restrict__ p, float s) {
  short8 r;
#pragma unroll
  for (int j = 0; j < 8; ++j) r[j] = f2bf(p[j] * s);
  return r;
}
__device__ __forceinline__ short4v load_w4s(const float* __restrict__ p, float s) {
  short4v r;
#pragma unroll
  for (int j = 0; j < 4; ++j) r[j] = f2bf(p[j] * s);
  return r;
}

__device__ __forceinline__ floatx4 mfma16(short4v a, short4v b, floatx4 c) {
#if __has_builtin(__builtin_amdgcn_mfma_f32_16x16x16bf16_1k)
  return __builtin_amdgcn_mfma_f32_16x16x16bf16_1k(a, b, c, 0, 0, 0);
#elif __has_builtin(__builtin_amdgcn_mfma_f32_16x16x16_bf16)
  return __builtin_amdgcn_mfma_f32_16x16x16_bf16(a, b, c, 0, 0, 0);
#else
  asm volatile("v_mfma_f32_16x16x16_bf16 %0, %1, %2, %0\n\ts_nop 7\n\ts_nop 7"
               : "+v"(c)
               : "v"(a), "v"(b));
  return c;
#endif
}

// R12 body (passing, 102us, VGPR=64) with the x/bias chunk compacted from a
// k=32 MFMA (short8 frags, 3/4 dead k-slots) to a k=16 MFMA (short4 frags,
// layout HW-verified in R3/R6: A k=q*4+j -> q0: W_ih cols 0-3, q1: cols
// 4-7, q2 j0: scaled bias, q3 dead; B: q0/q1 = x bf16, q2 = {1,0,0,0},
// q3 = 0). Weight regs 48->40, bx 8->4 -> target reported VGPR <=48-52.
// Session law: waves/CU ~= 760/VGPR_Count (fits R1/R2/R9/R10/R11/R12) --
// residency is VGPR-priced at ~2x textbook; this is the only remaining
// lever on the ~60us issue-work floor (VALUBusy 63% @ 3 waves/SIMD).
// No launch_bounds (R12 proved the default == (256,4) behavior).
// Numerics identical (absmax 1.953e-3): weights pre-scaled (i,f,o by
// -log2e, g by 2*log2e), grouped reciprocals, cell state pre-scaled by
// 2*log2e. Compact x staging + onesz row for the bias/zero B-lanes.
__global__ void lstm_kernel(
    const float* __restrict__ x, const float* __restrict__ W_ih,
    const float* __restrict__ W_hh, const float* __restrict__ b_ih,
    const float* __restrict__ b_hh, const float* __restrict__ W_fc,
    const float* __restrict__ b_fc, float* __restrict__ out) {
  __shared__ short hbuf[2][MSEQ][LDA];                 // 9216 B
  __shared__ __align__(16) short xbuf[T_][MSEQ][8];    // 6144 B
  __shared__ __align__(16) short onesz[8];             // {1.0,0..} + zeros

  const int tid = threadIdx.x;
  const int wave = tid >> 6;
  const int lane = tid & 63;
  const int m16 = lane & 15;
  const int q = lane >> 4;
  const int blk = blockIdx.x;

  // ---- A-operand weight fragments: lane row = unit wave*16+m16 ----
  const int urow = wave * 16 + m16;
  short8 wAh[4][2];   // k=32 h-chunks (32 VGPR)
  short4v wAx[4];     // k=16 x/bias chunk (8 VGPR)
#pragma unroll
  for (int g = 0; g < 4; ++g) {
    const float sg = (g == 2) ? TLOG2E : NLOG2E;
    const int grow = g * 64 + urow;
    const float* wr = W_hh + grow * 64;
    wAh[g][0] = load_w8s(wr + q * 8, sg);
    wAh[g][1] = load_w8s(wr + 32 + q * 8, sg);
    short4v xv = {0, 0, 0, 0};
    if (q < 2) {
      xv = load_w4s(W_ih + grow * 8 + q * 4, sg);   // k=q*4+j: x cols 0..7
    } else if (q == 2) {
      xv[0] = f2bf(sg * (b_ih[grow] + b_hh[grow]));  // k=8: bias column
    }
    wAx[g] = xv;
  }

  // ---- zero hbuf (h0 = 0, pads = 0); onesz row for bias/zero B-lanes ----
  {
    int* hp = (int*)hbuf;
#pragma unroll
    for (int i = tid; i < (2 * MSEQ * LDA) / 2; i += 256) hp[i] = 0;
    if (tid < 8) onesz[tid] = (tid == 0) ? (short)0x3F80 : (short)0;
  }
  __syncthreads();

  // ---- stage all 12 timesteps of x as bf16 (compact 16B rows) ----
  {
    const int xseq = tid >> 3, xc = tid & 7;
    const int s0 = blk * MSEQ + xseq;
    const int bidx = s0 / N_;
    const int nidx = s0 - bidx * N_;
    const float* xp = x + ((size_t)(bidx * T_) * N_ + nidx) * 8 + xc;
#pragma unroll
    for (int t = 0; t < T_; ++t)
      xbuf[t][xseq][xc] = f2bf(xp[(size_t)t * (N_ * 8)]);
  }
  __syncthreads();

  const floatx4 zacc = {0.0f, 0.0f, 0.0f, 0.0f};

  float cst[2][4];
#pragma unroll
  for (int nt = 0; nt < 2; ++nt)
#pragma unroll
    for (int r = 0; r < 4; ++r) cst[nt][r] = 0.0f;

  for (int t = 0; t < T_; ++t) {
    const int rb = t & 1, wb = rb ^ 1;

    // ---- phase 1: all LDS reads ----
    short8 b0[2], b1[2];
    short4v bx[2];
#pragma unroll
    for (int nt = 0; nt < 2; ++nt) {
      const int srow = nt * 16 + m16;
      b0[nt] = *(const short8*)&hbuf[rb][srow][q * 8];
      b1[nt] = *(const short8*)&hbuf[rb][srow][32 + q * 8];
      // B k16 x-frag: q0/q1 -> x[q*4..q*4+3], q2 -> {1,0,0,0}, q3 -> 0
      const short* bxp = (q < 2) ? &xbuf[t][srow][q * 4] : &onesz[(q - 2) * 4];
      bx[nt] = *(const short4v*)bxp;
    }

    // ---- phase 2: all 24 MFMAs into materialized accumulators ----
    floatx4 acc[2][4];
#pragma unroll
    for (int nt = 0; nt < 2; ++nt)
#pragma unroll
      for (int g = 0; g < 4; ++g) {
        floatx4 c = __builtin_amdgcn_mfma_f32_16x16x32_bf16(wAh[g][0], b0[nt], zacc, 0, 0, 0);
        c = __builtin_amdgcn_mfma_f32_16x16x32_bf16(wAh[g][1], b1[nt], c, 0, 0, 0);
        c = mfma16(wAx[g], bx[nt], c);
        acc[nt][g] = c;
      }

    // ---- phase 3a: all 32 gate exp2 (independent, stream the trans pipe)
    float di[2][4], df[2][4], dgv[2][4], dqv[2][4];
#pragma unroll
    for (int nt = 0; nt < 2; ++nt)
#pragma unroll
      for (int r = 0; r < 4; ++r) {
        di[nt][r] = 1.0f + __builtin_amdgcn_exp2f(acc[nt][0][r]);
        df[nt][r] = 1.0f + __builtin_amdgcn_exp2f(acc[nt][1][r]);
        dgv[nt][r] = 1.0f + __builtin_amdgcn_exp2f(acc[nt][2][r]);
        dqv[nt][r] = 1.0f + __builtin_amdgcn_exp2f(acc[nt][3][r]);
      }

    // ---- phase 3b: grouped rp across the nt pair (4 rcp instead of 8)
    float pa[2][4], pb[2][4], rp[2][4];
#pragma unroll
    for (int r = 0; r < 4; ++r) {
      pa[0][r] = di[0][r] * df[0][r];
      pb[0][r] = dgv[0][r] * dqv[0][r];
      pa[1][r] = di[1][r] * df[1][r];
      pb[1][r] = dgv[1][r] * dqv[1][r];
      const float PA = pa[0][r] * pb[0][r];
      const float PB = pa[1][r] * pb[1][r];
      const float R = __builtin_amdgcn_rcpf(PA * PB);
      rp[0][r] = R * PB;
      rp[1][r] = R * PA;
    }

    // ---- phase 3c: gate algebra + cell update + tanh-denominator exp2
    float ov[2][4], dt[2][4];
#pragma unroll
    for (int nt = 0; nt < 2; ++nt)
#pragma unroll
      for (int r = 0; r < 4; ++r) {
        const float fv = rp[nt][r] * di[nt][r] * pb[nt][r];      // f = 1/df
        ov[nt][r] = rp[nt][r] * pa[nt][r] * dgv[nt][r];          // o = 1/dq
        const float tg = fmaf(TLOG2E, dgv[nt][r], N2LOG2E);      // (dg-2)*2log2e
        const float ig = tg * rp[nt][r] * (df[nt][r] * dqv[nt][r]);
        const float cs = fmaf(fv, cst[nt][r], ig);               // c*2log2e
        cst[nt][r] = cs;
        dt[nt][r] = 1.0f + __builtin_amdgcn_exp2f(cs);
      }

    // ---- phase 3d: grouped tanh reciprocal per nt (1 rcp for 4 cells)
    unsigned long long pkv[2];
#pragma unroll
    for (int nt = 0; nt < 2; ++nt) {
      const float m01 = dt[nt][0] * dt[nt][1];
      const float m23 = dt[nt][2] * dt[nt][3];
      const float R = __builtin_amdgcn_rcpf(m01 * m23);
      const float r01 = R * m23, r23 = R * m01;
      float rdt[4];
      rdt[0] = r01 * dt[nt][1];
      rdt[1] = r01 * dt[nt][0];
      rdt[2] = r23 * dt[nt][3];
      rdt[3] = r23 * dt[nt][2];
      float hv[4];
#pragma unroll
      for (int r = 0; r < 4; ++r) {
        const float tw = ov[nt][r] + ov[nt][r];                  // 2*o
        hv[r] = fmaf(-tw, rdt[r], ov[nt][r]);                    // o*(1-2/dt)
      }
      pkv[nt] = (unsigned long long)pk_bf16(hv[0], hv[1]) |
                ((unsigned long long)pk_bf16(hv[2], hv[3]) << 32);
    }

    // ---- phase 4: h writes + barrier ----
#pragma unroll
    for (int nt = 0; nt < 2; ++nt) {
      const int srow = nt * 16 + m16;
      *(unsigned long long*)&hbuf[wb][srow][wave * 16 + q * 4] = pkv[nt];
    }
    __syncthreads();
  }

  // ---- final FC: y = h_T @ W_fc^T + b_fc; h_T is in hbuf[0] ----
  if (wave < 2) {
    short8 f0, f1;
    short8 z = {0, 0, 0, 0, 0, 0, 0, 0};
    if (m16 < 8) {
      const float* wr = W_fc + m16 * 64;
      f0 = load_w8s(wr + q * 8, 1.0f);
      f1 = load_w8s(wr + 32 + q * 8, 1.0f);
    } else {
      f0 = z;
      f1 = z;
    }
    const int srow = wave * 16 + m16;
    short8 h0 = *(const short8*)&hbuf[0][srow][q * 8];
    short8 h1 = *(const short8*)&hbuf[0][srow][32 + q * 8];
    floatx4 acc = __builtin_amdgcn_mfma_f32_16x16x32_bf16(f0, h0, zacc, 0, 0, 0);
    acc = __builtin_amdgcn_mfma_f32_16x16x32_bf16(f1, h1, acc, 0, 0, 0);
    if (q < 2) {
      const int orow = blk * MSEQ + srow;
#pragma unroll
      for (int r = 0; r < 4; ++r)
        out[orow * 8 + q * 4 + r] = acc[r] + b_fc[q * 4 + r];
    }
  }
}

extern "C" void kernel_launch(void* const* d_in, const int* in_sizes, int n_in,
                              void* d_out, int out_size, void* d_ws,
                              size_t ws_size, hipStream_t stream) {
  const float* x    = (const float*)d_in[0];
  const float* W_ih = (const float*)d_in[1];
  const float* W_hh = (const float*)d_in[2];
  const float* b_ih = (const float*)d_in[3];
  const float* b_hh = (const float*)d_in[4];
  const float* W_fc = (const float*)d_in[5];
  const float* b_fc = (const float*)d_in[6];
  float* out = (float*)d_out;
  hipLaunchKernelGGL(lstm_kernel, dim3(NBLK), dim3(256), 0, stream,
                     x, W_ih, W_hh, b_ih, b_hh, W_fc, b_fc, out);
}